// Round 17
// baseline (2261.936 us; speedup 1.0000x reference)
//
#include <hip/hip_runtime.h>

// numpy rounds every op separately — keep contraction off everywhere.
#pragma clang fp contract(off)

#define N_PTS 8192
#define C_DIM 64
#define NQ (3 * N_PTS)          // 24576 queries
#define G 64                    // grid cells per axis
#define NCELL (G * G)           // 4096
#define MARGIN 1.2e-5f          // >> 2*E(f32 formula ~3.5e-6) + binning/fp slop
#define HCELL (1.0f / 64.0f)
#define GROUP 8                 // lanes per query (r14 best)
#define QPB 32                  // queries per 256-thread block
#define BUILDBLKS 64            // one cell-row per build block
#define QBLOCKS (NQ / QPB)      // 768 query blocks
#define TOTALBLKS (BUILDBLKS + QBLOCKS)   // 832 <= 1024 co-resident capacity

// ws layout:
//   sorted   float4[8192]  @ 0        (cx, cy, sc, idx-bits)
//   starts   int[4097]     @ 131072
//   done     uint          @ 147968   (re-zeroed each call by hipMemsetAsync)

__device__ __forceinline__ unsigned int fsortkey(float f) {
    const unsigned int u = __float_as_uint(f);
    return (u & 0x80000000u) ? ~u : (u | 0x80000000u);
}
__device__ __forceinline__ float finvkey(unsigned int e) {
    const unsigned int u = (e & 0x80000000u) ? (e & 0x7fffffffu) : ~e;
    return __uint_as_float(u);
}

__device__ __forceinline__ void shift_query(int g, float x, float y,
                                            float sx, float sy,
                                            float& nx, float& ny) {
    if (g == 0)      { nx = x + sx; ny = y + sy; }
    else if (g == 1) { nx = x;      ny = y + sy; }
    else             { nx = x + sx; ny = y; }
}

// ---------------------------------------------------------------------------
// Fused kernel. Blocks [0,64): counting-sort build (one cell-row each; base
// offset = count(cy < myRow), no inter-block handshake) then release-add to
// `done`. Blocks [64,832): copy original values/coords (independent of the
// build, hides its latency), acquire-spin on done==64, then the r14 query
// body (3x3 scan -> U; exact candidate box; lex (d2,idx); fused gather).
// Co-residency: 832 blocks @ __launch_bounds__(256,4) -> >=1024 capacity.
// ---------------------------------------------------------------------------
__global__ __launch_bounds__(256, 4) void mega_kernel(
    const float2* __restrict__ coords2,
    const float4* __restrict__ values4,
    float4* __restrict__ sorted,
    int* __restrict__ starts,
    unsigned int* __restrict__ done,
    const float* __restrict__ spacing,
    const float* __restrict__ shift,
    float4* __restrict__ out_values4,
    float2* __restrict__ out_coords)
{
#pragma clang fp contract(off)
    __shared__ int s_starts[NCELL + 1];     // 16388 B (query phase)
    __shared__ unsigned int hist[G];        // build phase
    __shared__ unsigned int wred[4];
    __shared__ unsigned int baseSh;

    const int tid = threadIdx.x;

    if (blockIdx.x < BUILDBLKS) {
        // ================= build phase: this block owns cell-row myRow ====
        const int myRow = blockIdx.x;

        if (tid < G) hist[tid] = 0u;
        __syncthreads();

        // pass 1: histogram own row; count points in rows below
        int cnt = 0;
        for (int kk = 0; kk < 32; ++kk) {
            const int i = tid + 256 * kk;
            const float2 c = coords2[i];
            int cy = (int)(c.y * 64.0f); cy = min(max(cy, 0), G - 1);
            if (cy < myRow) {
                ++cnt;
            } else if (cy == myRow) {
                int cx = (int)(c.x * 64.0f); cx = min(max(cx, 0), G - 1);
                atomicAdd(&hist[cx], 1u);
            }
        }
        int cv = cnt;
        #pragma unroll
        for (int s = 32; s >= 1; s >>= 1) cv += __shfl_xor(cv, s, 64);
        if ((tid & 63) == 0) wred[tid >> 6] = (unsigned)cv;
        __syncthreads();
        if (tid == 0) baseSh = wred[0] + wred[1] + wred[2] + wred[3];
        __syncthreads();
        const unsigned base = baseSh;

        // scan the 64 cell counts (wave 0) -> absolute exclusive starts
        if (tid < G) {
            const unsigned h = hist[tid];
            unsigned v = h;
            #pragma unroll
            for (int s = 1; s < 64; s <<= 1) {
                const unsigned o = __shfl_up(v, s, 64);
                if (tid >= s) v += o;
            }
            const unsigned excl = base + v - h;
            starts[myRow * G + tid] = (int)excl;
            hist[tid] = excl;               // scatter cursor
        }
        if (myRow == 0 && tid == 0) starts[NCELL] = N_PTS;
        __syncthreads();

        // pass 2: scatter own row's points
        for (int kk = 0; kk < 32; ++kk) {
            const int i = tid + 256 * kk;
            const float2 c = coords2[i];
            int cy = (int)(c.y * 64.0f); cy = min(max(cy, 0), G - 1);
            if (cy == myRow) {
                int cx = (int)(c.x * 64.0f); cx = min(max(cx, 0), G - 1);
                const unsigned pos = atomicAdd(&hist[cx], 1u);
                const float p0 = c.x * c.x;     // separate rn ops
                const float p1 = c.y * c.y;
                const float sc = p0 + p1;
                sorted[pos] = make_float4(c.x, c.y, sc, __int_as_float(i));
            }
        }

        __threadfence();                    // device-visible before publish
        __syncthreads();
        if (tid == 0)
            __hip_atomic_fetch_add(done, 1u, __ATOMIC_RELEASE,
                                   __HIP_MEMORY_SCOPE_AGENT);
        return;
    }

    // ================= query phase ========================================
    const int qb = blockIdx.x - BUILDBLKS;  // 0..767
    const int tq = qb * 256 + tid;

    // free work while the build runs: copy original values + coords
    if (tq < N_PTS * 16) out_values4[tq] = values4[tq];
    if (tq < N_PTS)      out_coords[tq]  = coords2[tq];

    const float sx = spacing[0], sy = spacing[1];
    const float h0 = shift[0],   h1 = shift[1];

    // wait for the build (agent-scope acquire)
    while (__hip_atomic_load(done, __ATOMIC_ACQUIRE,
                             __HIP_MEMORY_SCOPE_AGENT) < BUILDBLKS)
        __builtin_amdgcn_s_sleep(16);

    const int lane = tid & (GROUP - 1);
    const int q    = qb * QPB + (tid >> 3);  // [0, NQ)
    const int g    = q >> 13;
    const int k    = q & (N_PTS - 1);

    const float4 me = sorted[k];            // early issue

    for (int i = tid; i <= NCELL; i += 256) s_starts[i] = starts[i];

    const int b = __float_as_int(me.w);     // original point index
    float nx, ny;
    shift_query(g, me.x, me.y, sx, sy, nx, ny);
    const float ax = nx - h0;
    const float ay = ny - h1;
    const float sa = (ax * ax) + (ay * ay);

    int cx = (int)floorf(ax * 64.0f); cx = min(max(cx, 0), G - 1);
    int cy = (int)floorf(ay * 64.0f); cy = min(max(cy, 0), G - 1);
    const float dxo = fmaxf(fmaxf(ax - 1.0f, -ax), 0.0f);   // x-overhang

    __syncthreads();

    float best = INFINITY;
    int   bi   = 0x7fffffff;

#define EVAL_BODY(PT)                                                       \
    {                                                                       \
        const float4 pt = (PT);                                             \
        const float p   = ax * pt.x;                                        \
        const float dv  = __builtin_fmaf(ay, pt.y, p);                      \
        const float t1  = sa + pt.z;                                        \
        const float d2  = t1 - (2.0f * dv);                                 \
        const int   j   = __float_as_int(pt.w);                             \
        if (d2 < best || (d2 == best && j < bi)) { best = d2; bi = j; }     \
    }

    // ---- step 1: 3x3 around clamped cell, flattened + batch-prefetched
    const int xa = max(cx - 1, 0), xb = min(cx + 1, G - 1);
    const int ya = max(cy - 1, 0), yb = min(cy + 1, G - 1);

    const int s0 = s_starts[ya * G + xa];
    const int e0 = s_starts[ya * G + xb + 1];
    int s1 = 0, e1 = 0, s2 = 0, e2 = 0;
    if (ya + 1 <= yb) { s1 = s_starts[(ya + 1) * G + xa]; e1 = s_starts[(ya + 1) * G + xb + 1]; }
    if (ya + 2 <= yb) { s2 = s_starts[(ya + 2) * G + xa]; e2 = s_starts[(ya + 2) * G + xb + 1]; }
    const int l0 = e0 - s0, l1 = e1 - s1;
    const int total = l0 + l1 + (e2 - s2);

    {
        const int i0 = lane, i1 = lane + 8, i2 = lane + 16;
        const bool v0 = i0 < total, v1 = i1 < total, v2 = i2 < total;
        float4 p0, p1, p2;
        int a0 = 0, a1 = 0, a2 = 0;
        if (v0) a0 = (i0 < l0) ? s0 + i0 : ((i0 < l0 + l1) ? s1 + (i0 - l0) : s2 + (i0 - l0 - l1));
        if (v1) a1 = (i1 < l0) ? s0 + i1 : ((i1 < l0 + l1) ? s1 + (i1 - l0) : s2 + (i1 - l0 - l1));
        if (v2) a2 = (i2 < l0) ? s0 + i2 : ((i2 < l0 + l1) ? s1 + (i2 - l0) : s2 + (i2 - l0 - l1));
        if (v0) p0 = sorted[a0];            // three independent loads,
        if (v1) p1 = sorted[a1];            // issued back-to-back
        if (v2) p2 = sorted[a2];
        if (v0) EVAL_BODY(p0)
        if (v1) EVAL_BODY(p1)
        if (v2) EVAL_BODY(p2)
        for (int idx = lane + 24; idx < total; idx += 8) {      // rare tail
            const int a = (idx < l0) ? s0 + idx
                        : ((idx < l0 + l1) ? s1 + (idx - l0) : s2 + (idx - l0 - l1));
            EVAL_BODY(sorted[a])
        }
    }

    unsigned long long key =
        ((unsigned long long)fsortkey(best) << 32) | (unsigned int)bi;
    #pragma unroll
    for (int m = 1; m < GROUP; m <<= 1) {
        const unsigned long long o = __shfl_xor(key, m, GROUP);
        if (o < key) key = o;
    }
    best = finvkey((unsigned int)(key >> 32));
    bi   = (int)(unsigned int)key;

    // ---- step 2: exact candidate box from U = best + MARGIN, rows in pairs
    const float U = best + MARGIN;

    float sr = sqrtf(fmaxf(U - dxo * dxo, 0.0f));
    sr = fminf(sr, 4.0f);                   // INF-safe; 4 covers whole grid
    const int ylo = max((int)floorf((ay - sr) * 64.0f), 0);
    const int yhi = min((int)floorf((ay + sr) * 64.0f), G - 1);

    float scw = fminf(sqrtf(U), 4.0f);
    const int xlo_c = max((int)floorf((ax - scw) * 64.0f), 0);
    const int xhi_c = min((int)floorf((ax + scw) * 64.0f), G - 1);

    const bool skip = (ylo >= ya) && (yhi <= yb) && (xlo_c >= xa) && (xhi_c <= xb);

    if (!skip) {
        for (int yy = ylo; yy <= yhi; yy += 2) {
            int ssA = 0, eeA = 0, ssB = 0, eeB = 0;
            {
                const float ry0 = (float)yy * HCELL;
                const float vy  = fmaxf(fmaxf(ay - ry0 - HCELL, ry0 - ay), 0.0f);
                const float r2  = U - vy * vy;
                if (r2 >= 0.0f) {
                    const float s = fminf(sqrtf(r2), 4.0f);
                    const int xl = max((int)floorf((ax - s) * 64.0f), 0);
                    const int xh = min((int)floorf((ax + s) * 64.0f), G - 1);
                    if (xl <= xh && !(yy >= ya && yy <= yb && xl >= xa && xh <= xb)) {
                        ssA = s_starts[yy * G + xl];
                        eeA = s_starts[yy * G + xh + 1];
                    }
                }
            }
            if (yy + 1 <= yhi) {
                const int y2 = yy + 1;
                const float ry0 = (float)y2 * HCELL;
                const float vy  = fmaxf(fmaxf(ay - ry0 - HCELL, ry0 - ay), 0.0f);
                const float r2  = U - vy * vy;
                if (r2 >= 0.0f) {
                    const float s = fminf(sqrtf(r2), 4.0f);
                    const int xl = max((int)floorf((ax - s) * 64.0f), 0);
                    const int xh = min((int)floorf((ax + s) * 64.0f), G - 1);
                    if (xl <= xh && !(y2 >= ya && y2 <= yb && xl >= xa && xh <= xb)) {
                        ssB = s_starts[y2 * G + xl];
                        eeB = s_starts[y2 * G + xh + 1];
                    }
                }
            }
            const int iA = ssA + lane, iB = ssB + lane;
            const bool vA = iA < eeA, vB = iB < eeB;
            float4 pA, pB;
            if (vA) pA = sorted[iA];
            if (vB) pB = sorted[iB];
            if (vA) EVAL_BODY(pA)
            if (vB) EVAL_BODY(pB)
            for (int i = ssA + lane + 8; i < eeA; i += 8) EVAL_BODY(sorted[i])
            for (int i = ssB + lane + 8; i < eeB; i += 8) EVAL_BODY(sorted[i])
        }
        key = ((unsigned long long)fsortkey(best) << 32) | (unsigned int)bi;
        #pragma unroll
        for (int m = 1; m < GROUP; m <<= 1) {
            const unsigned long long o = __shfl_xor(key, m, GROUP);
            if (o < key) key = o;
        }
        bi = (int)(unsigned int)key;
    }
#undef EVAL_BODY

    // ---- fused gather (r11/r14 pattern)
    bi = min(max(bi, 0), N_PTS - 1);        // defensive (no-op when correct)
    const int qi  = g * N_PTS + b;
    const int row = N_PTS + qi;
    out_values4[row * 16 + 2 * lane + 0] = values4[bi * 16 + 2 * lane + 0];
    out_values4[row * 16 + 2 * lane + 1] = values4[bi * 16 + 2 * lane + 1];
    if (lane == 0) out_coords[row] = make_float2(nx, ny);
}

extern "C" void kernel_launch(void* const* d_in, const int* in_sizes, int n_in,
                              void* d_out, int out_size, void* d_ws, size_t ws_size,
                              hipStream_t stream)
{
    const float* values  = (const float*)d_in[0];   // [8192,64]
    const float* coords  = (const float*)d_in[1];   // [8192,2]
    const float* spacing = (const float*)d_in[2];   // [2]
    const float* shift   = (const float*)d_in[3];   // [2]

    float* out_values = (float*)d_out;                          // [32768,64]
    float2* out_coords = (float2*)(out_values + (size_t)4 * N_PTS * C_DIM);

    char* ws = (char*)d_ws;
    float4* sorted      = (float4*)ws;              // @0
    int* starts         = (int*)(ws + 131072);
    unsigned int* done  = (unsigned int*)(ws + 147968);

    hipMemsetAsync((void*)done, 0, sizeof(unsigned int), stream);

    mega_kernel<<<TOTALBLKS, 256, 0, stream>>>(
        (const float2*)coords, (const float4*)values,
        sorted, starts, done, spacing, shift,
        (float4*)out_values, out_coords);
}

// Round 19
// 31.121 us; speedup vs baseline: 72.6819x; 72.6819x over previous
//
#include <hip/hip_runtime.h>

// numpy rounds every op separately — keep contraction off everywhere.
#pragma clang fp contract(off)

#define N_PTS 8192
#define C_DIM 64
#define NQ (3 * N_PTS)          // 24576 queries
#define G 64                    // grid cells per axis
#define NCELL (G * G)           // 4096
#define MARGIN 1.2e-5f          // >> 2*E(f32 formula ~3.5e-6) + binning/fp slop
#define HCELL (1.0f / 64.0f)
#define GROUP 8                 // lanes per query (r14 best)
#define QPB 32                  // queries per 256-thread block
#define QBLOCKS (NQ / QPB)      // 768 query blocks
#define COPYBLKS 128            // copy blocks in kernel 2 (64 rows each, 4 iters)
#define BUILDBLKS 64            // one cell-row per build block

// ws layout:
//   sorted   float4[8192]  @ 0        (cx, cy, sc, idx-bits)
//   starts   int[4097]     @ 131072

__device__ __forceinline__ unsigned int fsortkey(float f) {
    const unsigned int u = __float_as_uint(f);
    return (u & 0x80000000u) ? ~u : (u | 0x80000000u);
}
__device__ __forceinline__ float finvkey(unsigned int e) {
    const unsigned int u = (e & 0x80000000u) ? (e & 0x7fffffffu) : ~e;
    return __uint_as_float(u);
}

__device__ __forceinline__ void shift_query(int g, float x, float y,
                                            float sx, float sy,
                                            float& nx, float& ny) {
    if (g == 0)      { nx = x + sx; ny = y + sy; }
    else if (g == 1) { nx = x;      ny = y + sy; }
    else             { nx = x + sx; ny = y; }
}

// ---------------------------------------------------------------------------
// Kernel 1: pure build — 64 blocks x 256 threads, one cell-row each (logic
// verified in r17: base = count(cy < myRow), no inter-block communication).
// ---------------------------------------------------------------------------
__global__ __launch_bounds__(256) void build_kernel(
    const float2* __restrict__ coords2,
    float4* __restrict__ sorted,
    int* __restrict__ starts)
{
#pragma clang fp contract(off)
    __shared__ unsigned int hist[G];
    __shared__ unsigned int wred[4];
    __shared__ unsigned int baseSh;

    const int tid   = threadIdx.x;
    const int myRow = blockIdx.x;

    if (tid < G) hist[tid] = 0u;
    __syncthreads();

    // pass 1: histogram own row; count points in rows below
    int cnt = 0;
    for (int kk = 0; kk < 32; ++kk) {
        const int i = tid + 256 * kk;
        const float2 c = coords2[i];
        int cy = (int)(c.y * 64.0f); cy = min(max(cy, 0), G - 1);
        if (cy < myRow) {
            ++cnt;
        } else if (cy == myRow) {
            int cx = (int)(c.x * 64.0f); cx = min(max(cx, 0), G - 1);
            atomicAdd(&hist[cx], 1u);
        }
    }
    int cv = cnt;
    #pragma unroll
    for (int s = 32; s >= 1; s >>= 1) cv += __shfl_xor(cv, s, 64);
    if ((tid & 63) == 0) wred[tid >> 6] = (unsigned)cv;
    __syncthreads();
    if (tid == 0) baseSh = wred[0] + wred[1] + wred[2] + wred[3];
    __syncthreads();
    const unsigned base = baseSh;

    // scan the 64 cell counts (wave 0) -> absolute exclusive starts
    if (tid < G) {
        const unsigned h = hist[tid];
        unsigned v = h;
        #pragma unroll
        for (int s = 1; s < 64; s <<= 1) {
            const unsigned o = __shfl_up(v, s, 64);
            if (tid >= s) v += o;
        }
        const unsigned excl = base + v - h;
        starts[myRow * G + tid] = (int)excl;
        hist[tid] = excl;               // scatter cursor
    }
    if (myRow == 0 && tid == 0) starts[NCELL] = N_PTS;
    __syncthreads();

    // pass 2: scatter own row's points
    for (int kk = 0; kk < 32; ++kk) {
        const int i = tid + 256 * kk;
        const float2 c = coords2[i];
        int cy = (int)(c.y * 64.0f); cy = min(max(cy, 0), G - 1);
        if (cy == myRow) {
            int cx = (int)(c.x * 64.0f); cx = min(max(cx, 0), G - 1);
            const unsigned pos = atomicAdd(&hist[cx], 1u);
            const float p0 = c.x * c.x;     // separate rn ops
            const float p1 = c.y * c.y;
            const float sc = p0 + p1;
            sorted[pos] = make_float4(c.x, c.y, sc, __int_as_float(i));
        }
    }
}

// ---------------------------------------------------------------------------
// Kernel 2: blocks [0,768) = r14 query body verbatim. Blocks [768,896) =
// copy of original value rows + coords — 64 rows/block via 4 iterations of
// 16 rows (r18's bug: single iteration copied only 16 rows/block).
// ---------------------------------------------------------------------------
__global__ __launch_bounds__(256) void query_copy_kernel(
    const float4* __restrict__ sorted,
    const int* __restrict__ starts,
    const float4* __restrict__ values4,
    const float2* __restrict__ coords2,
    const float* __restrict__ spacing,
    const float* __restrict__ shift,
    float4* __restrict__ out_values4,
    float2* __restrict__ out_coords)
{
#pragma clang fp contract(off)
    const int tid = threadIdx.x;

    if (blockIdx.x >= QBLOCKS) {
        // ---- copy path: 64 rows per block = 4 iters x 16 rows
        const int blk = (int)blockIdx.x - QBLOCKS;
        const int c4  = tid & 15;
        #pragma unroll
        for (int it = 0; it < 4; ++it) {
            const int row = blk * 64 + it * 16 + (tid >> 4);
            out_values4[row * 16 + c4] = values4[row * 16 + c4];
            if (c4 == 0) out_coords[row] = coords2[row];
        }
        return;
    }

    __shared__ int s_starts[NCELL + 1];     // 16388 B

    const int lane = tid & (GROUP - 1);
    const int q    = blockIdx.x * QPB + (tid >> 3);  // [0, NQ)
    const int g    = q >> 13;
    const int k    = q & (N_PTS - 1);

    const float4 me = sorted[k];            // early issue

    for (int i = tid; i <= NCELL; i += 256) s_starts[i] = starts[i];

    const int b = __float_as_int(me.w);     // original point index
    float nx, ny;
    shift_query(g, me.x, me.y, spacing[0], spacing[1], nx, ny);
    const float ax = nx - shift[0];
    const float ay = ny - shift[1];
    const float sa = (ax * ax) + (ay * ay);

    int cx = (int)floorf(ax * 64.0f); cx = min(max(cx, 0), G - 1);
    int cy = (int)floorf(ay * 64.0f); cy = min(max(cy, 0), G - 1);
    const float dxo = fmaxf(fmaxf(ax - 1.0f, -ax), 0.0f);   // x-overhang

    __syncthreads();

    float best = INFINITY;
    int   bi   = 0x7fffffff;

#define EVAL_BODY(PT)                                                       \
    {                                                                       \
        const float4 pt = (PT);                                             \
        const float p   = ax * pt.x;                                        \
        const float dv  = __builtin_fmaf(ay, pt.y, p);                      \
        const float t1  = sa + pt.z;                                        \
        const float d2  = t1 - (2.0f * dv);                                 \
        const int   j   = __float_as_int(pt.w);                             \
        if (d2 < best || (d2 == best && j < bi)) { best = d2; bi = j; }     \
    }

    // ---- step 1: 3x3 around clamped cell, flattened + batch-prefetched
    const int xa = max(cx - 1, 0), xb = min(cx + 1, G - 1);
    const int ya = max(cy - 1, 0), yb = min(cy + 1, G - 1);

    const int s0 = s_starts[ya * G + xa];
    const int e0 = s_starts[ya * G + xb + 1];
    int s1 = 0, e1 = 0, s2 = 0, e2 = 0;
    if (ya + 1 <= yb) { s1 = s_starts[(ya + 1) * G + xa]; e1 = s_starts[(ya + 1) * G + xb + 1]; }
    if (ya + 2 <= yb) { s2 = s_starts[(ya + 2) * G + xa]; e2 = s_starts[(ya + 2) * G + xb + 1]; }
    const int l0 = e0 - s0, l1 = e1 - s1;
    const int total = l0 + l1 + (e2 - s2);

    {
        const int i0 = lane, i1 = lane + 8, i2 = lane + 16;
        const bool v0 = i0 < total, v1 = i1 < total, v2 = i2 < total;
        float4 p0, p1, p2;
        int a0 = 0, a1 = 0, a2 = 0;
        if (v0) a0 = (i0 < l0) ? s0 + i0 : ((i0 < l0 + l1) ? s1 + (i0 - l0) : s2 + (i0 - l0 - l1));
        if (v1) a1 = (i1 < l0) ? s0 + i1 : ((i1 < l0 + l1) ? s1 + (i1 - l0) : s2 + (i1 - l0 - l1));
        if (v2) a2 = (i2 < l0) ? s0 + i2 : ((i2 < l0 + l1) ? s1 + (i2 - l0) : s2 + (i2 - l0 - l1));
        if (v0) p0 = sorted[a0];            // three independent loads,
        if (v1) p1 = sorted[a1];            // issued back-to-back
        if (v2) p2 = sorted[a2];
        if (v0) EVAL_BODY(p0)
        if (v1) EVAL_BODY(p1)
        if (v2) EVAL_BODY(p2)
        for (int idx = lane + 24; idx < total; idx += 8) {      // rare tail
            const int a = (idx < l0) ? s0 + idx
                        : ((idx < l0 + l1) ? s1 + (idx - l0) : s2 + (idx - l0 - l1));
            EVAL_BODY(sorted[a])
        }
    }

    unsigned long long key =
        ((unsigned long long)fsortkey(best) << 32) | (unsigned int)bi;
    #pragma unroll
    for (int m = 1; m < GROUP; m <<= 1) {
        const unsigned long long o = __shfl_xor(key, m, GROUP);
        if (o < key) key = o;
    }
    best = finvkey((unsigned int)(key >> 32));
    bi   = (int)(unsigned int)key;

    // ---- step 2: exact candidate box from U = best + MARGIN, rows in pairs
    const float U = best + MARGIN;

    float sr = sqrtf(fmaxf(U - dxo * dxo, 0.0f));
    sr = fminf(sr, 4.0f);                   // INF-safe; 4 covers whole grid
    const int ylo = max((int)floorf((ay - sr) * 64.0f), 0);
    const int yhi = min((int)floorf((ay + sr) * 64.0f), G - 1);

    float scw = fminf(sqrtf(U), 4.0f);
    const int xlo_c = max((int)floorf((ax - scw) * 64.0f), 0);
    const int xhi_c = min((int)floorf((ax + scw) * 64.0f), G - 1);

    const bool skip = (ylo >= ya) && (yhi <= yb) && (xlo_c >= xa) && (xhi_c <= xb);

    if (!skip) {
        for (int yy = ylo; yy <= yhi; yy += 2) {
            int ssA = 0, eeA = 0, ssB = 0, eeB = 0;
            {
                const float ry0 = (float)yy * HCELL;
                const float vy  = fmaxf(fmaxf(ay - ry0 - HCELL, ry0 - ay), 0.0f);
                const float r2  = U - vy * vy;
                if (r2 >= 0.0f) {
                    const float s = fminf(sqrtf(r2), 4.0f);
                    const int xl = max((int)floorf((ax - s) * 64.0f), 0);
                    const int xh = min((int)floorf((ax + s) * 64.0f), G - 1);
                    if (xl <= xh && !(yy >= ya && yy <= yb && xl >= xa && xh <= xb)) {
                        ssA = s_starts[yy * G + xl];
                        eeA = s_starts[yy * G + xh + 1];
                    }
                }
            }
            if (yy + 1 <= yhi) {
                const int y2 = yy + 1;
                const float ry0 = (float)y2 * HCELL;
                const float vy  = fmaxf(fmaxf(ay - ry0 - HCELL, ry0 - ay), 0.0f);
                const float r2  = U - vy * vy;
                if (r2 >= 0.0f) {
                    const float s = fminf(sqrtf(r2), 4.0f);
                    const int xl = max((int)floorf((ax - s) * 64.0f), 0);
                    const int xh = min((int)floorf((ax + s) * 64.0f), G - 1);
                    if (xl <= xh && !(y2 >= ya && y2 <= yb && xl >= xa && xh <= xb)) {
                        ssB = s_starts[y2 * G + xl];
                        eeB = s_starts[y2 * G + xh + 1];
                    }
                }
            }
            const int iA = ssA + lane, iB = ssB + lane;
            const bool vA = iA < eeA, vB = iB < eeB;
            float4 pA, pB;
            if (vA) pA = sorted[iA];
            if (vB) pB = sorted[iB];
            if (vA) EVAL_BODY(pA)
            if (vB) EVAL_BODY(pB)
            for (int i = ssA + lane + 8; i < eeA; i += 8) EVAL_BODY(sorted[i])
            for (int i = ssB + lane + 8; i < eeB; i += 8) EVAL_BODY(sorted[i])
        }
        key = ((unsigned long long)fsortkey(best) << 32) | (unsigned int)bi;
        #pragma unroll
        for (int m = 1; m < GROUP; m <<= 1) {
            const unsigned long long o = __shfl_xor(key, m, GROUP);
            if (o < key) key = o;
        }
        bi = (int)(unsigned int)key;
    }
#undef EVAL_BODY

    // ---- fused gather (r11/r14 pattern)
    bi = min(max(bi, 0), N_PTS - 1);        // defensive (no-op when correct)
    const int qi  = g * N_PTS + b;
    const int row = N_PTS + qi;
    out_values4[row * 16 + 2 * lane + 0] = values4[bi * 16 + 2 * lane + 0];
    out_values4[row * 16 + 2 * lane + 1] = values4[bi * 16 + 2 * lane + 1];
    if (lane == 0) out_coords[row] = make_float2(nx, ny);
}

extern "C" void kernel_launch(void* const* d_in, const int* in_sizes, int n_in,
                              void* d_out, int out_size, void* d_ws, size_t ws_size,
                              hipStream_t stream)
{
    const float* values  = (const float*)d_in[0];   // [8192,64]
    const float* coords  = (const float*)d_in[1];   // [8192,2]
    const float* spacing = (const float*)d_in[2];   // [2]
    const float* shift   = (const float*)d_in[3];   // [2]

    float* out_values = (float*)d_out;                          // [32768,64]
    float2* out_coords = (float2*)(out_values + (size_t)4 * N_PTS * C_DIM);

    char* ws = (char*)d_ws;
    float4* sorted = (float4*)ws;                   // @0
    int* starts    = (int*)(ws + 131072);

    build_kernel<<<BUILDBLKS, 256, 0, stream>>>(
        (const float2*)coords, sorted, starts);

    query_copy_kernel<<<QBLOCKS + COPYBLKS, 256, 0, stream>>>(
        sorted, starts, (const float4*)values, (const float2*)coords,
        spacing, shift, (float4*)out_values, out_coords);
}

// Round 20
// 21.812 us; speedup vs baseline: 103.7006x; 1.4268x over previous
//
#include <hip/hip_runtime.h>

// numpy rounds every op separately — keep contraction off everywhere.
#pragma clang fp contract(off)

#define N_PTS 8192
#define C_DIM 64
#define NQ (3 * N_PTS)          // 24576 queries
#define G 64                    // grid cells per axis
#define NCELL (G * G)           // 4096
#define MARGIN 1.2e-5f          // >> 2*E(f32 formula ~3.5e-6) + binning/fp slop
#define HCELL (1.0f / 64.0f)
#define GROUP 8                 // lanes per query (empirical best, r14)
#define QPB 32                  // queries per 256-thread block
#define QBLOCKS (NQ / QPB)      // 768 query blocks
#define STRIPEBLKS 16           // build stripes (4 cell-rows each)
#define CPS (NCELL / STRIPEBLKS)// 256 cells per stripe
#define COPYBLKS 128            // copy blocks (64 value-rows each)

// ws layout:
//   sorted   float4[8192]  @ 0        (cx, cy, sc, idx-bits)
//   starts   int[4097]     @ 131072

__device__ __forceinline__ unsigned int fsortkey(float f) {
    const unsigned int u = __float_as_uint(f);
    return (u & 0x80000000u) ? ~u : (u | 0x80000000u);
}
__device__ __forceinline__ float finvkey(unsigned int e) {
    const unsigned int u = (e & 0x80000000u) ? (e & 0x7fffffffu) : ~e;
    return __uint_as_float(u);
}

__device__ __forceinline__ void shift_query(int g, float x, float y,
                                            float sx, float sy,
                                            float& nx, float& ny) {
    if (g == 0)      { nx = x + sx; ny = y + sy; }
    else if (g == 1) { nx = x;      ny = y + sy; }
    else             { nx = x + sx; ny = y; }
}

// ---------------------------------------------------------------------------
// Kernel 1 (r14-verbatim): blocks [0,16): striped counting sort. Blocks
// [16,144): copy original value rows + original coords.
// ---------------------------------------------------------------------------
__global__ __launch_bounds__(1024) void build_copy_kernel(
    const float2* __restrict__ coords2,
    const float4* __restrict__ values4,
    float4* __restrict__ sorted,
    int* __restrict__ starts,
    float4* __restrict__ out_values4,
    float2* __restrict__ out_coords)
{
#pragma clang fp contract(off)
    const int t = threadIdx.x;
    if (blockIdx.x >= STRIPEBLKS) {
        const int row = ((int)blockIdx.x - STRIPEBLKS) * 64 + (t >> 4);
        const int c4  = t & 15;
        out_values4[row * 16 + c4] = values4[row * 16 + c4];
        if (c4 == 0) out_coords[row] = coords2[row];
        return;
    }

    __shared__ unsigned int lhist[CPS];     // 1 KB
    __shared__ unsigned int wred[16];
    __shared__ unsigned int wsum2[4];
    __shared__ unsigned int baseSh;

    const int b      = blockIdx.x;
    const int myBase = b * CPS;
    const int lane   = t & 63;
    const int w      = t >> 6;

    if (t < CPS) lhist[t] = 0u;
    __syncthreads();

    float2 cpt[8];
    int    cell[8];
    int cnt = 0;
    #pragma unroll
    for (int k = 0; k < 8; ++k) {
        const int i = t + 1024 * k;
        const float2 c = coords2[i];
        cpt[k] = c;
        int cx = (int)(c.x * 64.0f); cx = min(max(cx, 0), G - 1);
        int cy = (int)(c.y * 64.0f); cy = min(max(cy, 0), G - 1);
        cell[k] = cy * G + cx;
        cnt += (cell[k] < myBase) ? 1 : 0;
        const int lc = cell[k] - myBase;
        if (lc >= 0 && lc < CPS) atomicAdd(&lhist[lc], 1u);
    }

    int cv = cnt;
    #pragma unroll
    for (int s = 32; s >= 1; s >>= 1) cv += __shfl_xor(cv, s, 64);
    if (lane == 0) wred[w] = (unsigned)cv;
    __syncthreads();
    if (t == 0) {
        unsigned s = 0;
        #pragma unroll
        for (int j = 0; j < 16; ++j) s += wred[j];
        baseSh = s;
    }
    __syncthreads();
    const unsigned base = baseSh;

    unsigned h = 0, v = 0;
    if (t < CPS) {
        h = lhist[t];
        v = h;
        #pragma unroll
        for (int s = 1; s < 64; s <<= 1) {
            const unsigned o = __shfl_up(v, s, 64);
            if (lane >= s) v += o;
        }
        if (lane == 63) wsum2[w] = v;
    }
    __syncthreads();
    if (t < CPS) {
        unsigned woff = 0;
        for (int j = 0; j < w; ++j) woff += wsum2[j];
        const unsigned excl = base + woff + v - h;
        starts[myBase + t] = (int)excl;
        lhist[t] = excl;
    }
    if (b == 0 && t == 0) starts[NCELL] = N_PTS;
    __syncthreads();

    #pragma unroll
    for (int k = 0; k < 8; ++k) {
        const int lc = cell[k] - myBase;
        if (lc >= 0 && lc < CPS) {
            const unsigned pos = atomicAdd(&lhist[lc], 1u);
            const float p0 = cpt[k].x * cpt[k].x;   // separate rn ops
            const float p1 = cpt[k].y * cpt[k].y;
            const float sc = p0 + p1;
            const int i = t + 1024 * k;
            sorted[pos] = make_float4(cpt[k].x, cpt[k].y, sc, __int_as_float(i));
        }
    }
}

// ---------------------------------------------------------------------------
// Kernel 2 (r14-verbatim except int4 s_starts staging). 8 lanes/query;
// starts cached in LDS. Step 1: 3x3 bounds, flattened spans, 3 masked batch
// loads. Step 2: exact candidate box, rows in pairs. Lex (d2,idx) ->
// bit-exact np.argmin. Fused gather.
// ---------------------------------------------------------------------------
__global__ __launch_bounds__(256) void query_kernel(
    const float4* __restrict__ sorted,
    const int* __restrict__ starts,
    const float4* __restrict__ values4,
    const float* __restrict__ spacing,
    const float* __restrict__ shift,
    float4* __restrict__ out_values4,
    float2* __restrict__ out_coords)
{
#pragma clang fp contract(off)
    __shared__ int s_starts[NCELL + 4];     // int4-aligned staging

    const int tid  = threadIdx.x;
    const int lane = tid & (GROUP - 1);
    const int q    = blockIdx.x * QPB + (tid >> 3);  // [0, NQ)
    const int g    = q >> 13;
    const int k    = q & (N_PTS - 1);

    const float4 me = sorted[k];            // early issue

    {   // stage starts as int4: 1024 vec loads + 1 scalar
        int4* dst4 = (int4*)s_starts;
        const int4* src4 = (const int4*)starts;
        #pragma unroll
        for (int i = tid; i < NCELL / 4; i += 256) dst4[i] = src4[i];
        if (tid == 0) s_starts[NCELL] = starts[NCELL];
    }

    const int b = __float_as_int(me.w);     // original point index
    float nx, ny;
    shift_query(g, me.x, me.y, spacing[0], spacing[1], nx, ny);
    const float ax = nx - shift[0];
    const float ay = ny - shift[1];
    const float sa = (ax * ax) + (ay * ay);

    int cx = (int)floorf(ax * 64.0f); cx = min(max(cx, 0), G - 1);
    int cy = (int)floorf(ay * 64.0f); cy = min(max(cy, 0), G - 1);
    const float dxo = fmaxf(fmaxf(ax - 1.0f, -ax), 0.0f);   // x-overhang

    __syncthreads();

    float best = INFINITY;
    int   bi   = 0x7fffffff;

#define EVAL_BODY(PT)                                                       \
    {                                                                       \
        const float4 pt = (PT);                                             \
        const float p   = ax * pt.x;                                        \
        const float dv  = __builtin_fmaf(ay, pt.y, p);                      \
        const float t1  = sa + pt.z;                                        \
        const float d2  = t1 - (2.0f * dv);                                 \
        const int   j   = __float_as_int(pt.w);                             \
        if (d2 < best || (d2 == best && j < bi)) { best = d2; bi = j; }     \
    }

    // ---- step 1: 3x3 around clamped cell, flattened + batch-prefetched
    const int xa = max(cx - 1, 0), xb = min(cx + 1, G - 1);
    const int ya = max(cy - 1, 0), yb = min(cy + 1, G - 1);

    const int s0 = s_starts[ya * G + xa];
    const int e0 = s_starts[ya * G + xb + 1];
    int s1 = 0, e1 = 0, s2 = 0, e2 = 0;
    if (ya + 1 <= yb) { s1 = s_starts[(ya + 1) * G + xa]; e1 = s_starts[(ya + 1) * G + xb + 1]; }
    if (ya + 2 <= yb) { s2 = s_starts[(ya + 2) * G + xa]; e2 = s_starts[(ya + 2) * G + xb + 1]; }
    const int l0 = e0 - s0, l1 = e1 - s1;
    const int total = l0 + l1 + (e2 - s2);

    {
        const int i0 = lane, i1 = lane + 8, i2 = lane + 16;
        const bool v0 = i0 < total, v1 = i1 < total, v2 = i2 < total;
        float4 p0, p1, p2;
        int a0 = 0, a1 = 0, a2 = 0;
        if (v0) a0 = (i0 < l0) ? s0 + i0 : ((i0 < l0 + l1) ? s1 + (i0 - l0) : s2 + (i0 - l0 - l1));
        if (v1) a1 = (i1 < l0) ? s0 + i1 : ((i1 < l0 + l1) ? s1 + (i1 - l0) : s2 + (i1 - l0 - l1));
        if (v2) a2 = (i2 < l0) ? s0 + i2 : ((i2 < l0 + l1) ? s1 + (i2 - l0) : s2 + (i2 - l0 - l1));
        if (v0) p0 = sorted[a0];            // three independent loads,
        if (v1) p1 = sorted[a1];            // issued back-to-back
        if (v2) p2 = sorted[a2];
        if (v0) EVAL_BODY(p0)
        if (v1) EVAL_BODY(p1)
        if (v2) EVAL_BODY(p2)
        for (int idx = lane + 24; idx < total; idx += 8) {      // rare tail
            const int a = (idx < l0) ? s0 + idx
                        : ((idx < l0 + l1) ? s1 + (idx - l0) : s2 + (idx - l0 - l1));
            EVAL_BODY(sorted[a])
        }
    }

    unsigned long long key =
        ((unsigned long long)fsortkey(best) << 32) | (unsigned int)bi;
    #pragma unroll
    for (int m = 1; m < GROUP; m <<= 1) {
        const unsigned long long o = __shfl_xor(key, m, GROUP);
        if (o < key) key = o;
    }
    best = finvkey((unsigned int)(key >> 32));
    bi   = (int)(unsigned int)key;

    // ---- step 2: exact candidate box from U = best + MARGIN, rows in pairs
    const float U = best + MARGIN;

    float sr = sqrtf(fmaxf(U - dxo * dxo, 0.0f));
    sr = fminf(sr, 4.0f);                   // INF-safe; 4 covers whole grid
    const int ylo = max((int)floorf((ay - sr) * 64.0f), 0);
    const int yhi = min((int)floorf((ay + sr) * 64.0f), G - 1);

    float scw = fminf(sqrtf(U), 4.0f);
    const int xlo_c = max((int)floorf((ax - scw) * 64.0f), 0);
    const int xhi_c = min((int)floorf((ax + scw) * 64.0f), G - 1);

    const bool skip = (ylo >= ya) && (yhi <= yb) && (xlo_c >= xa) && (xhi_c <= xb);

    if (!skip) {
        for (int yy = ylo; yy <= yhi; yy += 2) {
            int ssA = 0, eeA = 0, ssB = 0, eeB = 0;
            {
                const float ry0 = (float)yy * HCELL;
                const float vy  = fmaxf(fmaxf(ay - ry0 - HCELL, ry0 - ay), 0.0f);
                const float r2  = U - vy * vy;
                if (r2 >= 0.0f) {
                    const float s = fminf(sqrtf(r2), 4.0f);
                    const int xl = max((int)floorf((ax - s) * 64.0f), 0);
                    const int xh = min((int)floorf((ax + s) * 64.0f), G - 1);
                    if (xl <= xh && !(yy >= ya && yy <= yb && xl >= xa && xh <= xb)) {
                        ssA = s_starts[yy * G + xl];
                        eeA = s_starts[yy * G + xh + 1];
                    }
                }
            }
            if (yy + 1 <= yhi) {
                const int y2 = yy + 1;
                const float ry0 = (float)y2 * HCELL;
                const float vy  = fmaxf(fmaxf(ay - ry0 - HCELL, ry0 - ay), 0.0f);
                const float r2  = U - vy * vy;
                if (r2 >= 0.0f) {
                    const float s = fminf(sqrtf(r2), 4.0f);
                    const int xl = max((int)floorf((ax - s) * 64.0f), 0);
                    const int xh = min((int)floorf((ax + s) * 64.0f), G - 1);
                    if (xl <= xh && !(y2 >= ya && y2 <= yb && xl >= xa && xh <= xb)) {
                        ssB = s_starts[y2 * G + xl];
                        eeB = s_starts[y2 * G + xh + 1];
                    }
                }
            }
            const int iA = ssA + lane, iB = ssB + lane;
            const bool vA = iA < eeA, vB = iB < eeB;
            float4 pA, pB;
            if (vA) pA = sorted[iA];
            if (vB) pB = sorted[iB];
            if (vA) EVAL_BODY(pA)
            if (vB) EVAL_BODY(pB)
            for (int i = ssA + lane + 8; i < eeA; i += 8) EVAL_BODY(sorted[i])
            for (int i = ssB + lane + 8; i < eeB; i += 8) EVAL_BODY(sorted[i])
        }
        key = ((unsigned long long)fsortkey(best) << 32) | (unsigned int)bi;
        #pragma unroll
        for (int m = 1; m < GROUP; m <<= 1) {
            const unsigned long long o = __shfl_xor(key, m, GROUP);
            if (o < key) key = o;
        }
        bi = (int)(unsigned int)key;
    }
#undef EVAL_BODY

    // ---- fused gather (r11/r14 pattern)
    bi = min(max(bi, 0), N_PTS - 1);        // defensive (no-op when correct)
    const int qi  = g * N_PTS + b;
    const int row = N_PTS + qi;
    out_values4[row * 16 + 2 * lane + 0] = values4[bi * 16 + 2 * lane + 0];
    out_values4[row * 16 + 2 * lane + 1] = values4[bi * 16 + 2 * lane + 1];
    if (lane == 0) out_coords[row] = make_float2(nx, ny);
}

extern "C" void kernel_launch(void* const* d_in, const int* in_sizes, int n_in,
                              void* d_out, int out_size, void* d_ws, size_t ws_size,
                              hipStream_t stream)
{
    const float* values  = (const float*)d_in[0];   // [8192,64]
    const float* coords  = (const float*)d_in[1];   // [8192,2]
    const float* spacing = (const float*)d_in[2];   // [2]
    const float* shift   = (const float*)d_in[3];   // [2]

    float* out_values = (float*)d_out;                          // [32768,64]
    float2* out_coords = (float2*)(out_values + (size_t)4 * N_PTS * C_DIM);

    char* ws = (char*)d_ws;
    float4* sorted = (float4*)ws;                   // @0
    int* starts    = (int*)(ws + 131072);

    build_copy_kernel<<<STRIPEBLKS + COPYBLKS, 1024, 0, stream>>>(
        (const float2*)coords, (const float4*)values,
        sorted, starts, (float4*)out_values, out_coords);

    query_kernel<<<QBLOCKS, 256, 0, stream>>>(
        sorted, starts, (const float4*)values, spacing, shift,
        (float4*)out_values, out_coords);
}